// Round 7
// baseline (19.044 us; speedup 1.0000x reference)
//
#include <hip/hip_runtime.h>
#include <math.h>

#define KCL 64
#define NPTS 32768
#define NBATCH 8
#define BLOCK 256
#define PPT 4
#define PTS_PER_BLOCK (BLOCK * PPT)                  // 1024
#define NBLOCKS (NBATCH * NPTS / PTS_PER_BLOCK)      // 256  (== #CUs)
#define BLOCKS_PER_B (NPTS / PTS_PER_BLOCK)          // 32
#define MAGIC 0x5F3C0DE5u

// ws layout (4-byte words): [0..255] partials (float), [256..511] flags (uint)

// ---------------------------------------------------------------------------
// Single fused kernel.
// Fold (lane = cluster, wave 0): Horner-form quadratic record, 3 x float4:
//   s(p) = x*(g0 x + g3 y + g4 z + g6) + y*(g1 y + g5 z + g7)
//        + z*(g2 z + g8) + g9
//   with A = M^T M, t = M^T q, M = sqrt(0.5*log2 e) diag(1/s) R^T, q = M c:
//   g0..2 = -diag(A); g3,g4,g5 = -2*(A01,A02,A12); g6..8 = 2t;
//   g9 = log2(-cst) - |q|^2       (constants always < 0)
//   F0=(g0,g3,g4,g6) F1=(g1,g5,g7,g2) F2=(g8,g9,-,-)
//   sdf = -sum_k exp2(s_k)
// K-loop: register double-buffer (prefetch k+1's 3 ds_read_b128 during k's
// 9 fma x 4 points) -> LDS latency hidden at 1 wave/SIMD.
// Completion: partial -> ws, release MAGIC flag; block 0 acquire-spins on all
// 256 flags (all blocks co-resident: 256 blocks, 256 CUs, no cyclic wait),
// reduces deterministically, writes out, resets flags for next graph replay.
// First call: stale flag == MAGIC has probability ~2^-32/word — accepted.
// ---------------------------------------------------------------------------
__global__ __launch_bounds__(BLOCK) void point_loss_kernel(
    const float4* __restrict__ pts,
    const float*  __restrict__ constants,
    const float*  __restrict__ scales,
    const float*  __restrict__ rotations,
    const float*  __restrict__ centers,
    float*        __restrict__ partials,
    unsigned int* __restrict__ flags,
    float*        __restrict__ out)
{
    __shared__ float4 cl4[KCL][3];
    __shared__ float wave_sums[BLOCK / 64];

    const int tid = threadIdx.x;
    const int bid = blockIdx.x;
    const int b   = bid / BLOCKS_PER_B;

    // ---- fold phase: wave 0, lane = cluster ----
    if (tid < KCL) {
        const int base = b * KCL + tid;
        const float rx = rotations[3 * base + 0];
        const float ry = rotations[3 * base + 1];
        const float rz = rotations[3 * base + 2];
        const float sx = sinf(rx), cx = cosf(rx);
        const float sy = sinf(ry), cy = cosf(ry);
        const float sz = sinf(rz), cz = cosf(rz);

        float R[3][3];
        R[0][0] = cz * cy; R[0][1] = cz * sy * sx - sz * cx; R[0][2] = cz * sy * cx + sz * sx;
        R[1][0] = sz * cy; R[1][1] = sz * sy * sx + cz * cx; R[1][2] = sz * sy * cx - cz * sx;
        R[2][0] = -sy;     R[2][1] = cy * sx;                R[2][2] = cy * cx;

        const float SC = 0.84932184f;  // sqrt(0.5 * log2(e))
        const float inv[3] = { SC / scales[3 * base + 0],
                               SC / scales[3 * base + 1],
                               SC / scales[3 * base + 2] };
        const float c0 = centers[3 * base + 0];
        const float c1 = centers[3 * base + 1];
        const float c2 = centers[3 * base + 2];

        float M[3][3], q[3];
        #pragma unroll
        for (int i = 0; i < 3; ++i) {
            M[i][0] = R[0][i] * inv[i];
            M[i][1] = R[1][i] * inv[i];
            M[i][2] = R[2][i] * inv[i];
            q[i] = M[i][0] * c0 + M[i][1] * c1 + M[i][2] * c2;
        }
        float A[3][3], t[3];
        #pragma unroll
        for (int j = 0; j < 3; ++j) {
            #pragma unroll
            for (int l = 0; l < 3; ++l)
                A[j][l] = M[0][j] * M[0][l] + M[1][j] * M[1][l] + M[2][j] * M[2][l];
            t[j] = M[0][j] * q[0] + M[1][j] * q[1] + M[2][j] * q[2];
        }
        const float cst = constants[base];
        const float g9 = log2f(-cst) - (q[0]*q[0] + q[1]*q[1] + q[2]*q[2]);

        cl4[tid][0] = make_float4(-A[0][0], -2.0f * A[0][1], -2.0f * A[0][2], 2.0f * t[0]);
        cl4[tid][1] = make_float4(-A[1][1], -2.0f * A[1][2], 2.0f * t[1], -A[2][2]);
        cl4[tid][2] = make_float4(2.0f * t[2], g9, 0.0f, 0.0f);
    }
    __syncthreads();

    // ---- point phase: 4 points per thread, Horner form ----
    const int n0 = b * NPTS + (bid % BLOCKS_PER_B) * PTS_PER_BLOCK + tid;
    float X[PPT], Y[PPT], Z[PPT], W[PPT];
    #pragma unroll
    for (int j = 0; j < PPT; ++j) {
        const float4 p = pts[n0 + j * BLOCK];
        X[j] = p.x; Y[j] = p.y; Z[j] = p.z; W[j] = p.w;
    }

    float acc[PPT] = {0.0f, 0.0f, 0.0f, 0.0f};
    float4 F0 = cl4[0][0], F1 = cl4[0][1], F2 = cl4[0][2];
    #pragma unroll 4
    for (int k = 0; k < KCL; ++k) {
        const int kn = (k + 1) & (KCL - 1);
        const float4 N0 = cl4[kn][0];
        const float4 N1 = cl4[kn][1];
        const float4 N2 = cl4[kn][2];
        #pragma unroll
        for (int j = 0; j < PPT; ++j) {
            const float t1 = fmaf(F0.x, X[j], fmaf(F0.y, Y[j], fmaf(F0.z, Z[j], F0.w)));
            const float t2 = fmaf(F1.x, Y[j], fmaf(F1.y, Z[j], F1.z));
            const float t3 = fmaf(F1.w, Z[j], F2.x);
            const float s  = fmaf(X[j], t1, fmaf(Y[j], t2, fmaf(Z[j], t3, F2.y)));
            acc[j] += __builtin_amdgcn_exp2f(s);
        }
        F0 = N0; F1 = N1; F2 = N2;
    }

    // ---- loss terms ----
    float term = 0.0f;
    #pragma unroll
    for (int j = 0; j < PPT; ++j) {
        const float sdf = -acc[j];
        const float gt  = (W[j] > 0.0f) ? 1.0f : 0.0f;
        const float z   = 100.0f * (sdf + 0.07f);
        const float pr  = 1.0f / (1.0f + __builtin_amdgcn_exp2f(-1.44269504f * z));
        const float w   = 10.0f - 9.0f * gt;
        const float d   = gt - pr;
        term = fmaf(w * d, d, term);
    }

    #pragma unroll
    for (int off = 32; off > 0; off >>= 1)
        term += __shfl_down(term, off, 64);

    if ((tid & 63) == 0) wave_sums[tid >> 6] = term;
    __syncthreads();

    if (tid == 0) {
        float s = 0.0f;
        #pragma unroll
        for (int i = 0; i < BLOCK / 64; ++i) s += wave_sums[i];
        partials[bid] = s;
        __hip_atomic_store(&flags[bid], MAGIC,
                           __ATOMIC_RELEASE, __HIP_MEMORY_SCOPE_AGENT);
    }

    // ---- block 0: final reduce once all 256 partials have arrived ----
    if (bid == 0) {
        unsigned int f;
        do {
            f = __hip_atomic_load(&flags[tid],
                                  __ATOMIC_ACQUIRE, __HIP_MEMORY_SCOPE_AGENT);
        } while (f != MAGIC);
        float v = __hip_atomic_load(&partials[tid],
                                    __ATOMIC_RELAXED, __HIP_MEMORY_SCOPE_AGENT);
        __hip_atomic_store(&flags[tid], 0u,
                           __ATOMIC_RELAXED, __HIP_MEMORY_SCOPE_AGENT);

        #pragma unroll
        for (int off = 32; off > 0; off >>= 1)
            v += __shfl_down(v, off, 64);

        __syncthreads();                       // wave_sums reuse barrier
        if ((tid & 63) == 0) wave_sums[tid >> 6] = v;
        __syncthreads();

        if (tid == 0) {
            const float tot = wave_sums[0] + wave_sums[1] + wave_sums[2] + wave_sums[3];
            out[0] = tot * (1.0f / (NBATCH * (float)NPTS));
        }
    }
}

extern "C" void kernel_launch(void* const* d_in, const int* in_sizes, int n_in,
                              void* d_out, int out_size, void* d_ws, size_t ws_size,
                              hipStream_t stream) {
    const float4* pts       = (const float4*)d_in[0];
    const float*  constants = (const float*)d_in[1];
    const float*  scales    = (const float*)d_in[2];
    const float*  rotations = (const float*)d_in[3];
    const float*  centers   = (const float*)d_in[4];
    float*        out       = (float*)d_out;
    float*        partials  = (float*)d_ws;
    unsigned int* flags     = (unsigned int*)d_ws + NBLOCKS;

    point_loss_kernel<<<NBLOCKS, BLOCK, 0, stream>>>(
        pts, constants, scales, rotations, centers, partials, flags, out);
}

// Round 8
// 15.204 us; speedup vs baseline: 1.2526x; 1.2526x over previous
//
#include <hip/hip_runtime.h>
#include <math.h>

#define KCL 64
#define NPTS 32768
#define NBATCH 8
#define BLOCK 256
#define PPT 4
#define PTS_PER_BLOCK (BLOCK * PPT)                  // 1024
#define NBLOCKS (NBATCH * NPTS / PTS_PER_BLOCK)      // 256  (== #CUs)
#define BLOCKS_PER_B (NPTS / PTS_PER_BLOCK)          // 32

// ---------------------------------------------------------------------------
// Main kernel (identical math to R6, repacked records):
//   s(p) = g0 x^2 + g1 y^2 + g2 z^2 + g3 xy + g4 xz + g5 yz
//        + g6 x + g7 y + g8 z + g9,   sdf = -sum_k exp2(s_k)
//   A = M^T M, t = M^T q, M = sqrt(0.5*log2 e) diag(1/s) R^T, q = M c
//   g0..2=-diag(A); g3,g4,g5=-2*(A01,A02,A12); g6..8=2t; g9=log2(-cst)-|q|^2
// LDS record: F0=(g0,g3,g4,g6) float4, F1=(g1,g5,g7,g2) float4, F2=(g8,g9)
// float2 -> per cluster 2x ds_read_b128 + 1x ds_read_b64 (wave-uniform
// broadcast, conflict-free). PPT=4 -> 1 block/CU, 1 wave/SIMD, LDS pipe
// ~7.7k cyc/CU. Partials to ws; no atomics, no fences (inter-kernel
// ordering makes partials visible to the reduce dispatch).
// ---------------------------------------------------------------------------
__global__ __launch_bounds__(BLOCK) void point_loss_kernel(
    const float4* __restrict__ pts,
    const float*  __restrict__ constants,
    const float*  __restrict__ scales,
    const float*  __restrict__ rotations,
    const float*  __restrict__ centers,
    float*        __restrict__ partials)
{
    __shared__ float4 clA[KCL];
    __shared__ float4 clB[KCL];
    __shared__ float2 clC[KCL];
    __shared__ float wave_sums[BLOCK / 64];

    const int tid = threadIdx.x;
    const int bid = blockIdx.x;
    const int b   = bid / BLOCKS_PER_B;

    // ---- fold phase: wave 0, lane = cluster ----
    if (tid < KCL) {
        const int base = b * KCL + tid;
        const float rx = rotations[3 * base + 0];
        const float ry = rotations[3 * base + 1];
        const float rz = rotations[3 * base + 2];
        const float sx = sinf(rx), cx = cosf(rx);
        const float sy = sinf(ry), cy = cosf(ry);
        const float sz = sinf(rz), cz = cosf(rz);

        float R[3][3];
        R[0][0] = cz * cy; R[0][1] = cz * sy * sx - sz * cx; R[0][2] = cz * sy * cx + sz * sx;
        R[1][0] = sz * cy; R[1][1] = sz * sy * sx + cz * cx; R[1][2] = sz * sy * cx - cz * sx;
        R[2][0] = -sy;     R[2][1] = cy * sx;                R[2][2] = cy * cx;

        const float SC = 0.84932184f;  // sqrt(0.5 * log2(e))
        const float inv[3] = { SC / scales[3 * base + 0],
                               SC / scales[3 * base + 1],
                               SC / scales[3 * base + 2] };
        const float c0 = centers[3 * base + 0];
        const float c1 = centers[3 * base + 1];
        const float c2 = centers[3 * base + 2];

        float M[3][3], q[3];
        #pragma unroll
        for (int i = 0; i < 3; ++i) {
            M[i][0] = R[0][i] * inv[i];
            M[i][1] = R[1][i] * inv[i];
            M[i][2] = R[2][i] * inv[i];
            q[i] = M[i][0] * c0 + M[i][1] * c1 + M[i][2] * c2;
        }
        float A[3][3], t[3];
        #pragma unroll
        for (int j = 0; j < 3; ++j) {
            #pragma unroll
            for (int l = 0; l < 3; ++l)
                A[j][l] = M[0][j] * M[0][l] + M[1][j] * M[1][l] + M[2][j] * M[2][l];
            t[j] = M[0][j] * q[0] + M[1][j] * q[1] + M[2][j] * q[2];
        }
        const float cst = constants[base];
        const float g9 = log2f(-cst) - (q[0]*q[0] + q[1]*q[1] + q[2]*q[2]);

        clA[tid] = make_float4(-A[0][0], -2.0f * A[0][1], -2.0f * A[0][2], 2.0f * t[0]);
        clB[tid] = make_float4(-A[1][1], -2.0f * A[1][2], 2.0f * t[1], -A[2][2]);
        clC[tid] = make_float2(2.0f * t[2], g9);
    }
    __syncthreads();

    // ---- point phase: 4 points per thread ----
    const int n0 = b * NPTS + (bid % BLOCKS_PER_B) * PTS_PER_BLOCK + tid;
    float X[PPT], Y[PPT], Z[PPT], W[PPT];
    #pragma unroll
    for (int j = 0; j < PPT; ++j) {
        const float4 p = pts[n0 + j * BLOCK];
        X[j] = p.x; Y[j] = p.y; Z[j] = p.z; W[j] = p.w;
    }

    float acc[PPT] = {0.0f, 0.0f, 0.0f, 0.0f};
    #pragma unroll 8
    for (int k = 0; k < KCL; ++k) {
        const float4 F0 = clA[k];
        const float4 F1 = clB[k];
        const float2 F2 = clC[k];
        #pragma unroll
        for (int j = 0; j < PPT; ++j) {
            // s = x*(g0 x + g3 y + g4 z + g6) + y*(g1 y + g5 z + g7)
            //   + z*(g2 z + g8) + g9
            const float t1 = fmaf(F0.x, X[j], fmaf(F0.y, Y[j], fmaf(F0.z, Z[j], F0.w)));
            const float t2 = fmaf(F1.x, Y[j], fmaf(F1.y, Z[j], F1.z));
            const float t3 = fmaf(F1.w, Z[j], F2.x);
            const float s  = fmaf(X[j], t1, fmaf(Y[j], t2, fmaf(Z[j], t3, F2.y)));
            acc[j] += __builtin_amdgcn_exp2f(s);
        }
    }

    // ---- loss terms ----
    float term = 0.0f;
    #pragma unroll
    for (int j = 0; j < PPT; ++j) {
        const float sdf = -acc[j];
        const float gt  = (W[j] > 0.0f) ? 1.0f : 0.0f;
        const float z   = 100.0f * (sdf + 0.07f);
        const float pr  = 1.0f / (1.0f + __builtin_amdgcn_exp2f(-1.44269504f * z));
        const float w   = 10.0f - 9.0f * gt;
        const float d   = gt - pr;
        term = fmaf(w * d, d, term);
    }

    #pragma unroll
    for (int off = 32; off > 0; off >>= 1)
        term += __shfl_down(term, off, 64);

    if ((tid & 63) == 0) wave_sums[tid >> 6] = term;
    __syncthreads();

    if (tid == 0) {
        float s = 0.0f;
        #pragma unroll
        for (int i = 0; i < BLOCK / 64; ++i) s += wave_sums[i];
        partials[bid] = s;
    }
}

// ---------------------------------------------------------------------------
// Final reduce: 1 wave, 4 partials per lane.
// ---------------------------------------------------------------------------
__global__ __launch_bounds__(64) void reduce_kernel(
    const float* __restrict__ partials,
    float*       __restrict__ out)
{
    const int tid = threadIdx.x;
    float s = partials[tid] + partials[tid + 64]
            + partials[tid + 128] + partials[tid + 192];

    #pragma unroll
    for (int off = 32; off > 0; off >>= 1)
        s += __shfl_down(s, off, 64);

    if (tid == 0)
        out[0] = s * (1.0f / (NBATCH * (float)NPTS));
}

extern "C" void kernel_launch(void* const* d_in, const int* in_sizes, int n_in,
                              void* d_out, int out_size, void* d_ws, size_t ws_size,
                              hipStream_t stream) {
    const float4* pts       = (const float4*)d_in[0];
    const float*  constants = (const float*)d_in[1];
    const float*  scales    = (const float*)d_in[2];
    const float*  rotations = (const float*)d_in[3];
    const float*  centers   = (const float*)d_in[4];
    float* out      = (float*)d_out;
    float* partials = (float*)d_ws;

    point_loss_kernel<<<NBLOCKS, BLOCK, 0, stream>>>(
        pts, constants, scales, rotations, centers, partials);
    reduce_kernel<<<1, 64, 0, stream>>>(partials, out);
}